// Round 2
// baseline (191.089 us; speedup 1.0000x reference)
//
#include <hip/hip_runtime.h>
#include <cmath>

// PositionIntervalLoss: B=65536 rows, F=300.
// One wave per row, 4 rows per 256-thread block.
// Lane l (<60) owns elements [5l, 5l+5); everything register-resident except
// the peak list / mids / per-segment den,num accumulators (small LDS arrays).

constexpr int FLEN = 300;
constexpr int RPB  = 4;
constexpr int SMAX = 152;

__global__ __launch_bounds__(256, 8)
void pil_kernel(const float* __restrict__ in, float* __restrict__ out,
                double bk0, double bk1, double bk2, double bk3)
{
    const int w    = threadIdx.x >> 6;
    const int lane = threadIdx.x & 63;
    const int row  = blockIdx.x * RPB + w;

    __shared__ int   ps_s [RPB][SMAX];   // sorted peak positions
    __shared__ int   md_s [RPB][SMAX];   // floor midpoints of consecutive peaks
    __shared__ float den_s[RPB][SMAX];   // per-segment sum exp
    __shared__ float num_s[RPB][SMAX];   // per-segment sum exp*freq

    int*   ps  = ps_s[w];
    int*   md  = md_s[w];
    float* den = den_s[w];
    float* num = num_s[w];

    for (int s = lane; s < SMAX; s += 64) { den[s] = 0.f; num[s] = 0.f; }

    const float* rin = in + (size_t)row * FLEN;
    const int  base = lane * 5;
    const bool act  = (lane < 60);

    // ---- load own 5 raw values (registers), halo via shfl ----
    float r0=0.f, r1=0.f, r2=0.f, r3=0.f, r4=0.f;
    if (act) {
        r0 = rin[base + 0]; r1 = rin[base + 1]; r2 = rin[base + 2];
        r3 = rin[base + 3]; r4 = rin[base + 4];
    }
    float l2 = __shfl_up(r2, 1);     // raw[base-3]
    float l3 = __shfl_up(r3, 1);     // raw[base-2]
    float l4 = __shfl_up(r4, 1);     // raw[base-1]
    float h0 = __shfl_down(r0, 1);   // raw[base+5]
    float h1 = __shfl_down(r1, 1);   // raw[base+6]
    float h2 = __shfl_down(r2, 1);   // raw[base+7]
    if (lane == 0)  { l2 = 0.f; l3 = 0.f; l4 = 0.f; }   // zero 'same' padding
    if (lane >= 59) { h0 = 0.f; h1 = 0.f; h2 = 0.f; }

    // ---- 7-tap symmetric Gaussian blur, fp64 accumulate (fp32 coeffs) ----
    float f[5];
    {
        double dd[11] = { (double)l2, (double)l3, (double)l4,
                          (double)r0, (double)r1, (double)r2, (double)r3, (double)r4,
                          (double)h0, (double)h1, (double)h2 };
        #pragma unroll
        for (int j = 0; j < 5; ++j) {
            double acc = bk3 *  dd[j+3]
                       + bk0 * (dd[j]   + dd[j+6])
                       + bk1 * (dd[j+1] + dd[j+5])
                       + bk2 * (dd[j+2] + dd[j+4]);
            f[j] = (float)acc;
        }
    }

    // ---- strict peaks (boundary = -inf sentinel), wave-scan compaction ----
    float fm1 = __shfl_up(f[4], 1);
    float fp1 = __shfl_down(f[0], 1);
    if (lane == 0)  fm1 = -__builtin_inff();
    if (lane >= 59) fp1 = -__builtin_inff();

    unsigned pk = 0; int cnt = 0;
    if (act) {
        float lft = fm1;
        #pragma unroll
        for (int j = 0; j < 5; ++j) {
            float rgt = (j < 4) ? f[j+1] : fp1;
            bool p = (f[j] > lft) && (f[j] > rgt);
            pk |= (unsigned)p << j;
            cnt += p;
            lft = f[j];
        }
    }

    int incl = cnt;
    #pragma unroll
    for (int dlt = 1; dlt < 64; dlt <<= 1) {
        int v = __shfl_up(incl, dlt);
        if (lane >= dlt) incl += v;
    }
    const int P = __shfl(incl, 63);
    int off = incl - cnt;
    if (act && pk) {
        #pragma unroll
        for (int j = 0; j < 5; ++j)
            if ((pk >> j) & 1u) ps[off++] = base + j;
    }
    __syncthreads();

    // ---- midpoints (segment dividers) ----
    const int M = (P > 1) ? (P - 1) : 0;   // number of dividers
    for (int j = lane; j < M; j += 64)
        md[j] = (ps[j] + ps[j + 1]) >> 1;
    __syncthreads();

    // ---- element-parallel softargmax accumulation over [0, 299) ----
    // seg_id(i) = #{ mids <= i }; per-lane run-aggregated atomic flush.
    if (act) {
        int lo = 0, hi = M;
        while (lo < hi) { int m = (lo + hi) >> 1; if (md[m] <= base) lo = m + 1; else hi = m; }
        int cur = lo;
        float aD = 0.f, aN = 0.f;
        #pragma unroll
        for (int j = 0; j < 5; ++j) {
            int i = base + j;
            if (i < FLEN - 1) {
                int s = cur;
                while (s < M && md[s] <= i) ++s;
                if (s != cur) {
                    if (aD > 0.f) {
                        atomicAdd(&den[cur], aD);
                        atomicAdd(&num[cur], aN);
                        aD = 0.f; aN = 0.f;
                    }
                    cur = s;
                }
                // exp(f) directly: |f| <= ~3 here, identical to stable form
                float e  = __expf(f[j]);
                float fr = fmaf((float)(i - 99), 0.02f, -1.0f);  // ((i+1)-100)/100*2-1
                aD += e;
                aN  = fmaf(e, fr, aN);
            }
        }
        if (aD > 0.f) { atomicAdd(&den[cur], aD); atomicAdd(&num[cur], aN); }
    }
    __syncthreads();

    // ---- per-segment finalize + wave reduction ----
    const int nseg = (P > 0) ? P : 1;
    float sum_in = 0.f; int any_in = 0;
    float m1 = -__builtin_inff(), m2 = -__builtin_inff();
    for (int s = lane; s < nseg; s += 64) {
        float sm  = num[s] / den[s];          // den >= min exp > 0
        float nsq = -(sm * sm);
        bool  ii  = (sm > -1.0f) && (sm < 1.0f);
        if (ii) { sum_in += nsq; any_in = 1; }
        if (nsq > m1) { m2 = m1; m1 = nsq; } else { m2 = fmaxf(m2, nsq); }
    }

    #pragma unroll
    for (int dlt = 32; dlt >= 1; dlt >>= 1) {
        sum_in += __shfl_xor(sum_in, dlt);
        any_in |= __shfl_xor(any_in, dlt);
        float o1 = __shfl_xor(m1, dlt);
        float o2 = __shfl_xor(m2, dlt);
        float n1 = fmaxf(m1, o1);
        float n2 = fmaxf(fminf(m1, o1), fmaxf(m2, o2));
        m1 = n1; m2 = n2;
    }

    if (lane == 0) {
        float t2 = m1 + ((m2 > -__builtin_inff()) ? m2 : 0.0f);
        out[row] = any_in ? sum_in : t2;
    }
}

extern "C" void kernel_launch(void* const* d_in, const int* in_sizes, int n_in,
                              void* d_out, int out_size, void* d_ws, size_t ws_size,
                              hipStream_t stream) {
    const float* in  = (const float*)d_in[0];
    float*       out = (float*)d_out;
    const int B = in_sizes[0] / FLEN;          // 65536

    // Gaussian kernel sigma=2, l=7: double, normalized, rounded to fp32
    // (matching jnp.asarray(k/k.sum(), float32)), widened back to double.
    double k[7], s = 0.0;
    for (int t = 0; t < 7; ++t) {
        double x = -3.0 + (double)t;
        k[t] = exp(-0.5 * x * x / 4.0);
        s += k[t];
    }
    double bk0 = (double)(float)(k[0] / s);
    double bk1 = (double)(float)(k[1] / s);
    double bk2 = (double)(float)(k[2] / s);
    double bk3 = (double)(float)(k[3] / s);

    pil_kernel<<<B / RPB, 256, 0, stream>>>(in, out, bk0, bk1, bk2, bk3);
}

// Round 4
// 138.962 us; speedup vs baseline: 1.3751x; 1.3751x over previous
//
#include <hip/hip_runtime.h>
#include <cmath>

// PositionIntervalLoss: B=65536 rows, F=300. One wave per row, 4 rows/block.
// Lane l (<60) owns elements [5l,5l+5). Register-resident blur + peak detect
// (ballot compaction); segment softargmax via row-wide FP64 prefix sums of
// (exp, exp*freq) so each segment is an O(1) prefix difference with no
// fp32 cancellation (den/num exact to ~1e-13, then rounded to fp32).

constexpr int FLEN = 300;
constexpr int RPB  = 4;
constexpr int SMAX = 152;

__global__ __launch_bounds__(256, 7)
void pil_kernel(const float* __restrict__ in, float* __restrict__ out,
                double bk0, double bk1, double bk2, double bk3)
{
    const int w    = threadIdx.x >> 6;
    const int lane = threadIdx.x & 63;
    const int row  = blockIdx.x * RPB + w;

    __shared__ int     ps_s[RPB][SMAX];   // sorted peak positions
    __shared__ double2 eg_s[RPB][FLEN];   // eg[t] = (sum_{u<t} e_u, sum_{u<t} e_u*fr_u)

    int*     ps = ps_s[w];
    double2* eg = eg_s[w];

    const float* rin  = in + (size_t)row * FLEN;
    const int    base = lane * 5;
    const bool   act  = (lane < 60);
    const int    bC   = act ? base : 295;          // clamp OOB lanes (unused)

    // ---- load own 5 raw values; halo via shfl ----
    float r0 = rin[bC+0], r1 = rin[bC+1], r2 = rin[bC+2], r3 = rin[bC+3], r4 = rin[bC+4];
    float l2 = __shfl_up(r2, 1), l3 = __shfl_up(r3, 1), l4 = __shfl_up(r4, 1);
    float h0 = __shfl_down(r0, 1), h1 = __shfl_down(r1, 1), h2 = __shfl_down(r2, 1);
    if (lane == 0)  { l2 = 0.f; l3 = 0.f; l4 = 0.f; }   // conv 'SAME' zero pad
    if (lane >= 59) { h0 = 0.f; h1 = 0.f; h2 = 0.f; }

    // ---- 7-tap symmetric blur, fp64 FMA accumulate (fp32-rounded coeffs) ----
    const double d0=(double)l2, d1=(double)l3, d2=(double)l4, d3=(double)r0,
                 d4=(double)r1, d5=(double)r2, d6=(double)r3, d7=(double)r4,
                 d8=(double)h0, d9=(double)h1, d10=(double)h2;
    float f[5];
    f[0] = (float)fma(bk0, d0+d6,  fma(bk1, d1+d5, fma(bk2, d2+d4, bk3*d3)));
    f[1] = (float)fma(bk0, d1+d7,  fma(bk1, d2+d6, fma(bk2, d3+d5, bk3*d4)));
    f[2] = (float)fma(bk0, d2+d8,  fma(bk1, d3+d7, fma(bk2, d4+d6, bk3*d5)));
    f[3] = (float)fma(bk0, d3+d9,  fma(bk1, d4+d8, fma(bk2, d5+d7, bk3*d6)));
    f[4] = (float)fma(bk0, d4+d10, fma(bk1, d5+d9, fma(bk2, d6+d8, bk3*d7)));

    // ---- strict peaks (boundary = -inf sentinel) ----
    float fm1 = __shfl_up(f[4], 1);
    float fp1 = __shfl_down(f[0], 1);
    if (lane == 0)  fm1 = -__builtin_inff();
    if (lane >= 59) fp1 = -__builtin_inff();

    bool p[5];
    {
        float lft = fm1;
        #pragma unroll
        for (int j = 0; j < 5; ++j) {
            float rgt = (j < 4) ? f[j+1] : fp1;
            p[j] = act && (f[j] > lft) && (f[j] > rgt);
            lft = f[j];
        }
    }

    // ---- compaction via ballot (no scan chain) ----
    unsigned long long b0 = __ballot(p[0]), b1 = __ballot(p[1]), b2 = __ballot(p[2]),
                       b3 = __ballot(p[3]), b4 = __ballot(p[4]);
    const unsigned long long below = (1ull << lane) - 1ull;
    int off = __popcll(b0 & below) + __popcll(b1 & below) + __popcll(b2 & below)
            + __popcll(b3 & below) + __popcll(b4 & below);
    const int P = __popcll(b0) + __popcll(b1) + __popcll(b2) + __popcll(b3) + __popcll(b4);
    #pragma unroll
    for (int j = 0; j < 5; ++j)
        if (p[j]) ps[off++] = base + j;

    // ---- per-element exp / freq; lane totals in fp64 ----
    float e5[5], fr5[5];
    double tE = 0.0, tG = 0.0;
    #pragma unroll
    for (int j = 0; j < 5; ++j) {
        int  i = base + j;
        bool v = act && (i < FLEN - 1);
        e5[j]  = v ? __expf(f[j]) : 0.f;    // |f|<~3: unstable softmax identical
        fr5[j] = ((float)(i - 99) / 100.0f) * 2.0f - 1.0f;  // ((i+1)-100)/100*2-1
        tE += (double)e5[j];
        tG  = fma((double)e5[j], (double)fr5[j], tG);
    }

    // ---- wave inclusive scan of lane totals (fp64) ----
    double sE = tE, sG = tG;
    #pragma unroll
    for (int d = 1; d < 64; d <<= 1) {
        double a = __shfl_up(sE, d), b = __shfl_up(sG, d);
        if (lane >= d) { sE += a; sG += b; }
    }

    // ---- per-element inclusive prefixes: recompute intra-lane running sums
    //      (same op order as tE/tG accumulation -> identical rounding) ----
    double runE = sE - tE, runG = sG - tG;   // exclusive prefix of lane totals
    if (lane == 63) eg[0] = make_double2(0.0, 0.0);
    #pragma unroll
    for (int j = 0; j < 5; ++j) {
        int i = base + j;
        runE += (double)e5[j];
        runG  = fma((double)e5[j], (double)fr5[j], runG);
        if (act && i <= FLEN - 2)
            eg[i + 1] = make_double2(runE, runG);
    }
    __syncthreads();

    // ---- per-segment softargmax = prefix difference; O(1) per segment ----
    const int nseg = (P > 0) ? P : 1;
    float sum_in = 0.f; int any_in = 0;
    float m1 = -__builtin_inff(), m2 = -__builtin_inff();
    for (int s = lane; s < nseg; s += 64) {
        int im = (s > 0) ? s - 1 : 0;
        int ip = (s < P - 1) ? s + 1 : im;
        int pm = ps[im], pc = ps[(P > 0) ? s : 0], pn = ps[ip];
        int lo = (s == 0)        ? 0        : (int)(((unsigned)pm + (unsigned)pc) >> 1);
        int hi = (s == nseg - 1) ? FLEN - 1 : (int)(((unsigned)pc + (unsigned)pn) >> 1);
        double2 a = eg[lo], b = eg[hi];
        float den = (float)(b.x - a.x);         // exact to ~1e-13, >= min exp > 0
        float num = (float)(b.y - a.y);
        float sm  = num / den;
        float nsq = -(sm * sm);
        bool  ii  = (sm > -1.0f) && (sm < 1.0f);
        if (ii) { sum_in += nsq; any_in = 1; }
        if (nsq > m1) { m2 = m1; m1 = nsq; } else { m2 = fmaxf(m2, nsq); }
    }

    // ---- wave butterfly reduction: sum, any, top-2 merge ----
    #pragma unroll
    for (int d = 32; d >= 1; d >>= 1) {
        sum_in += __shfl_xor(sum_in, d);
        any_in |= __shfl_xor(any_in, d);
        float o1 = __shfl_xor(m1, d);
        float o2 = __shfl_xor(m2, d);
        float n1 = fmaxf(m1, o1);
        float n2 = fmaxf(fminf(m1, o1), fmaxf(m2, o2));
        m1 = n1; m2 = n2;
    }

    if (lane == 0) {
        float t2 = m1 + ((m2 > -__builtin_inff()) ? m2 : 0.0f);
        out[row] = any_in ? sum_in : t2;
    }
}

extern "C" void kernel_launch(void* const* d_in, const int* in_sizes, int n_in,
                              void* d_out, int out_size, void* d_ws, size_t ws_size,
                              hipStream_t stream) {
    const float* in  = (const float*)d_in[0];
    float*       out = (float*)d_out;
    const int B = in_sizes[0] / FLEN;          // 65536

    // Gaussian kernel sigma=2, l=7: double, normalized, rounded to fp32
    // (matching jnp.asarray(k/k.sum(), float32)), widened back to double.
    double k[7], s = 0.0;
    for (int t = 0; t < 7; ++t) {
        double x = -3.0 + (double)t;
        k[t] = exp(-0.5 * x * x / 4.0);
        s += k[t];
    }
    double bk0 = (double)(float)(k[0] / s);
    double bk1 = (double)(float)(k[1] / s);
    double bk2 = (double)(float)(k[2] / s);
    double bk3 = (double)(float)(k[3] / s);

    pil_kernel<<<B / RPB, 256, 0, stream>>>(in, out, bk0, bk1, bk2, bk3);
}

// Round 5
// 126.776 us; speedup vs baseline: 1.5073x; 1.0961x over previous
//
#include <hip/hip_runtime.h>
#include <cmath>

// PositionIntervalLoss: B=65536 rows, F=300. One wave per row, 4 rows/block.
// Lane l (<60) owns elements [5l,5l+5). Register-resident fp64 blur + peak
// detect (ballot compaction); segment softargmax via row-wide FP64 prefix
// sums of (exp, exp*freq) -> O(1) prefix difference per segment, no
// cancellation. ps stored as ushort so LDS = 20416 B -> 8 blocks/CU.

constexpr int FLEN = 300;
constexpr int RPB  = 4;
constexpr int SMAX = 152;

__global__ __launch_bounds__(256, 8)
void pil_kernel(const float* __restrict__ in, float* __restrict__ out,
                double bk0, double bk1, double bk2, double bk3)
{
    const int w    = threadIdx.x >> 6;
    const int lane = threadIdx.x & 63;
    const int row  = blockIdx.x * RPB + w;

    __shared__ double2        eg_s[RPB][FLEN];   // eg[t]=(sum_{u<t} e_u, sum_{u<t} e_u*fr_u)
    __shared__ unsigned short ps_s[RPB][SMAX];   // sorted peak positions

    double2*        eg = eg_s[w];
    unsigned short* ps = ps_s[w];

    const float* rin  = in + (size_t)row * FLEN;
    const int    base = lane * 5;
    const bool   act  = (lane < 60);
    const int    bC   = act ? base : 295;          // clamp OOB lanes (unused)

    // ---- load own 5 raw values; halo via shfl ----
    float r0 = rin[bC+0], r1 = rin[bC+1], r2 = rin[bC+2], r3 = rin[bC+3], r4 = rin[bC+4];
    float l2 = __shfl_up(r2, 1), l3 = __shfl_up(r3, 1), l4 = __shfl_up(r4, 1);
    float h0 = __shfl_down(r0, 1), h1 = __shfl_down(r1, 1), h2 = __shfl_down(r2, 1);
    if (lane == 0)  { l2 = 0.f; l3 = 0.f; l4 = 0.f; }   // conv 'SAME' zero pad
    if (lane >= 59) { h0 = 0.f; h1 = 0.f; h2 = 0.f; }

    // ---- 7-tap symmetric blur, fp64 FMA accumulate (fp32-rounded coeffs) ----
    const double d0=(double)l2, d1=(double)l3, d2=(double)l4, d3=(double)r0,
                 d4=(double)r1, d5=(double)r2, d6=(double)r3, d7=(double)r4,
                 d8=(double)h0, d9=(double)h1, d10=(double)h2;
    float f[5];
    f[0] = (float)fma(bk0, d0+d6,  fma(bk1, d1+d5, fma(bk2, d2+d4, bk3*d3)));
    f[1] = (float)fma(bk0, d1+d7,  fma(bk1, d2+d6, fma(bk2, d3+d5, bk3*d4)));
    f[2] = (float)fma(bk0, d2+d8,  fma(bk1, d3+d7, fma(bk2, d4+d6, bk3*d5)));
    f[3] = (float)fma(bk0, d3+d9,  fma(bk1, d4+d8, fma(bk2, d5+d7, bk3*d6)));
    f[4] = (float)fma(bk0, d4+d10, fma(bk1, d5+d9, fma(bk2, d6+d8, bk3*d7)));

    // ---- strict peaks (boundary = -inf sentinel) ----
    float fm1 = __shfl_up(f[4], 1);
    float fp1 = __shfl_down(f[0], 1);
    if (lane == 0)  fm1 = -__builtin_inff();
    if (lane >= 59) fp1 = -__builtin_inff();

    bool p[5];
    {
        float lft = fm1;
        #pragma unroll
        for (int j = 0; j < 5; ++j) {
            float rgt = (j < 4) ? f[j+1] : fp1;
            p[j] = act && (f[j] > lft) && (f[j] > rgt);
            lft = f[j];
        }
    }

    // ---- compaction via ballot (no scan chain) ----
    unsigned long long b0 = __ballot(p[0]), b1 = __ballot(p[1]), b2 = __ballot(p[2]),
                       b3 = __ballot(p[3]), b4 = __ballot(p[4]);
    const unsigned long long below = (1ull << lane) - 1ull;
    int off = __popcll(b0 & below) + __popcll(b1 & below) + __popcll(b2 & below)
            + __popcll(b3 & below) + __popcll(b4 & below);
    const int P = __popcll(b0) + __popcll(b1) + __popcll(b2) + __popcll(b3) + __popcll(b4);
    #pragma unroll
    for (int j = 0; j < 5; ++j)
        if (p[j]) ps[off++] = (unsigned short)(base + j);

    // ---- per-element exp / freq; lane totals in fp64 ----
    float e5[5], fr5[5];
    double tE = 0.0, tG = 0.0;
    #pragma unroll
    for (int j = 0; j < 5; ++j) {
        int  i = base + j;
        bool v = act && (i < FLEN - 1);
        e5[j]  = v ? __expf(f[j]) : 0.f;    // |f|<~3: unstable softmax identical
        fr5[j] = fmaf((float)(i - 99), 0.02f, -1.0f);   // ((i+1)-100)/100*2-1
        tE += (double)e5[j];
        tG  = fma((double)e5[j], (double)fr5[j], tG);
    }

    // ---- wave inclusive scan of lane totals (fp64) ----
    double sE = tE, sG = tG;
    #pragma unroll
    for (int d = 1; d < 64; d <<= 1) {
        double a = __shfl_up(sE, d), b = __shfl_up(sG, d);
        if (lane >= d) { sE += a; sG += b; }
    }

    // ---- per-element inclusive prefixes: recompute intra-lane running sums
    //      (same op order as tE/tG accumulation -> identical rounding) ----
    double runE = sE - tE, runG = sG - tG;   // exclusive prefix of lane totals
    if (lane == 63) eg[0] = make_double2(0.0, 0.0);
    #pragma unroll
    for (int j = 0; j < 5; ++j) {
        int i = base + j;
        runE += (double)e5[j];
        runG  = fma((double)e5[j], (double)fr5[j], runG);
        if (act && i <= FLEN - 2)
            eg[i + 1] = make_double2(runE, runG);
    }
    __syncthreads();

    // ---- per-segment softargmax = prefix difference; O(1) per segment ----
    const int nseg = (P > 0) ? P : 1;
    float sum_in = 0.f; int any_in = 0;
    float nsq_l[3]; int nsq_n = 0;           // this lane's nsq values (<=3 segs/lane)
    for (int s = lane; s < nseg; s += 64) {
        int im = (s > 0) ? s - 1 : 0;
        int ip = (s < P - 1) ? s + 1 : im;
        int pm = ps[im], pc = ps[(P > 0) ? s : 0], pn = ps[ip];
        int lo = (s == 0)        ? 0        : ((pm + pc) >> 1);
        int hi = (s == nseg - 1) ? FLEN - 1 : ((pc + pn) >> 1);
        double2 a = eg[lo], b = eg[hi];
        float den = (float)(b.x - a.x);         // exact to ~1e-13, > 0
        float num = (float)(b.y - a.y);
        float sm  = num / den;
        float nsq = -(sm * sm);
        bool  ii  = (sm > -1.0f) && (sm < 1.0f);
        if (ii) { sum_in += nsq; any_in = 1; }
        if (nsq_n < 3) nsq_l[nsq_n] = nsq;
        nsq_n += 1;
    }

    // ---- common path: some segment in-interval (one ballot decides) ----
    if (__ballot(any_in) != 0ull) {
        #pragma unroll
        for (int d = 32; d >= 1; d >>= 1) sum_in += __shfl_xor(sum_in, d);
        if (lane == 0) out[row] = sum_in;
    } else {
        // rare fallback: sum of two largest nsq among valid segments
        float m1 = -__builtin_inff(), m2 = -__builtin_inff();
        for (int q = 0; q < nsq_n; ++q) {
            float nsq = nsq_l[q];
            if (nsq > m1) { m2 = m1; m1 = nsq; } else { m2 = fmaxf(m2, nsq); }
        }
        #pragma unroll
        for (int d = 32; d >= 1; d >>= 1) {
            float o1 = __shfl_xor(m1, d);
            float o2 = __shfl_xor(m2, d);
            float n1 = fmaxf(m1, o1);
            float n2 = fmaxf(fminf(m1, o1), fmaxf(m2, o2));
            m1 = n1; m2 = n2;
        }
        if (lane == 0) {
            float t2 = m1 + ((m2 > -__builtin_inff()) ? m2 : 0.0f);
            out[row] = t2;
        }
    }
}

extern "C" void kernel_launch(void* const* d_in, const int* in_sizes, int n_in,
                              void* d_out, int out_size, void* d_ws, size_t ws_size,
                              hipStream_t stream) {
    const float* in  = (const float*)d_in[0];
    float*       out = (float*)d_out;
    const int B = in_sizes[0] / FLEN;          // 65536

    // Gaussian kernel sigma=2, l=7: double, normalized, rounded to fp32
    // (matching jnp.asarray(k/k.sum(), float32)), widened back to double.
    double k[7], s = 0.0;
    for (int t = 0; t < 7; ++t) {
        double x = -3.0 + (double)t;
        k[t] = exp(-0.5 * x * x / 4.0);
        s += k[t];
    }
    double bk0 = (double)(float)(k[0] / s);
    double bk1 = (double)(float)(k[1] / s);
    double bk2 = (double)(float)(k[2] / s);
    double bk3 = (double)(float)(k[3] / s);

    pil_kernel<<<B / RPB, 256, 0, stream>>>(in, out, bk0, bk1, bk2, bk3);
}

// Round 6
// 126.215 us; speedup vs baseline: 1.5140x; 1.0044x over previous
//
#include <hip/hip_runtime.h>
#include <cmath>

// PositionIntervalLoss: B=65536 rows, F=300. One wave per row, 2 rows/block.
// Lane l (<60) owns elements [5l,5l+5). Register-resident fp64 blur + peak
// detect (ballot + mbcnt compaction); segment softargmax via row-wide FP64
// prefix sums of (exp, exp*freq) -> O(1) prefix difference per segment.
// No __syncthreads: each wave owns its row's LDS slice; same-wave DS ops
// execute in order, so a wave-local waitcnt fence suffices.

constexpr int FLEN = 300;
constexpr int RPB  = 2;
constexpr int SMAX = 152;

__global__ __launch_bounds__(128, 8)
void pil_kernel(const float* __restrict__ in, float* __restrict__ out,
                double bk0, double bk1, double bk2, double bk3)
{
    const int w    = threadIdx.x >> 6;
    const int lane = threadIdx.x & 63;
    const int row  = blockIdx.x * RPB + w;

    __shared__ double2        eg_s[RPB][FLEN];   // eg[t]=(sum_{u<t} e_u, sum_{u<t} e_u*fr_u)
    __shared__ unsigned short ps_s[RPB][SMAX];   // sorted peak positions

    double2*        eg = eg_s[w];
    unsigned short* ps = ps_s[w];

    const float* rin  = in + (size_t)row * FLEN;
    const int    base = lane * 5;
    const bool   act  = (lane < 60);
    const int    bC   = act ? base : 295;          // clamp OOB lanes (unused)

    // ---- load own 5 raw values; halo via shfl ----
    float r0 = rin[bC+0], r1 = rin[bC+1], r2 = rin[bC+2], r3 = rin[bC+3], r4 = rin[bC+4];
    float l2 = __shfl_up(r2, 1), l3 = __shfl_up(r3, 1), l4 = __shfl_up(r4, 1);
    float h0 = __shfl_down(r0, 1), h1 = __shfl_down(r1, 1), h2 = __shfl_down(r2, 1);
    if (lane == 0)  { l2 = 0.f; l3 = 0.f; l4 = 0.f; }   // conv 'SAME' zero pad
    if (lane >= 59) { h0 = 0.f; h1 = 0.f; h2 = 0.f; }

    // ---- 7-tap symmetric blur, fp64 FMA accumulate (fp32-rounded coeffs) ----
    const double d0=(double)l2, d1=(double)l3, d2=(double)l4, d3=(double)r0,
                 d4=(double)r1, d5=(double)r2, d6=(double)r3, d7=(double)r4,
                 d8=(double)h0, d9=(double)h1, d10=(double)h2;
    float f[5];
    f[0] = (float)fma(bk0, d0+d6,  fma(bk1, d1+d5, fma(bk2, d2+d4, bk3*d3)));
    f[1] = (float)fma(bk0, d1+d7,  fma(bk1, d2+d6, fma(bk2, d3+d5, bk3*d4)));
    f[2] = (float)fma(bk0, d2+d8,  fma(bk1, d3+d7, fma(bk2, d4+d6, bk3*d5)));
    f[3] = (float)fma(bk0, d3+d9,  fma(bk1, d4+d8, fma(bk2, d5+d7, bk3*d6)));
    f[4] = (float)fma(bk0, d4+d10, fma(bk1, d5+d9, fma(bk2, d6+d8, bk3*d7)));

    // ---- strict peaks (boundary = -inf sentinel) ----
    float fm1 = __shfl_up(f[4], 1);
    float fp1 = __shfl_down(f[0], 1);
    if (lane == 0)  fm1 = -__builtin_inff();
    if (lane >= 59) fp1 = -__builtin_inff();

    bool p[5];
    {
        float lft = fm1;
        #pragma unroll
        for (int j = 0; j < 5; ++j) {
            float rgt = (j < 4) ? f[j+1] : fp1;
            p[j] = act && (f[j] > lft) && (f[j] > rgt);
            lft = f[j];
        }
    }

    // ---- compaction: ballot + mbcnt (popcount of mask & lanemask_lt) ----
    unsigned long long b0 = __ballot(p[0]), b1 = __ballot(p[1]), b2 = __ballot(p[2]),
                       b3 = __ballot(p[3]), b4 = __ballot(p[4]);
    int off = 0;
    off = __builtin_amdgcn_mbcnt_lo((unsigned)b0, off);
    off = __builtin_amdgcn_mbcnt_hi((unsigned)(b0 >> 32), off);
    off = __builtin_amdgcn_mbcnt_lo((unsigned)b1, off);
    off = __builtin_amdgcn_mbcnt_hi((unsigned)(b1 >> 32), off);
    off = __builtin_amdgcn_mbcnt_lo((unsigned)b2, off);
    off = __builtin_amdgcn_mbcnt_hi((unsigned)(b2 >> 32), off);
    off = __builtin_amdgcn_mbcnt_lo((unsigned)b3, off);
    off = __builtin_amdgcn_mbcnt_hi((unsigned)(b3 >> 32), off);
    off = __builtin_amdgcn_mbcnt_lo((unsigned)b4, off);
    off = __builtin_amdgcn_mbcnt_hi((unsigned)(b4 >> 32), off);
    const int P = __popcll(b0) + __popcll(b1) + __popcll(b2) + __popcll(b3) + __popcll(b4);
    #pragma unroll
    for (int j = 0; j < 5; ++j)
        if (p[j]) ps[off++] = (unsigned short)(base + j);

    // ---- per-element exp / freq; intra-lane inclusive prefixes in fp64 ----
    double cE[5], cG[5];
    double tE = 0.0, tG = 0.0;
    #pragma unroll
    for (int j = 0; j < 5; ++j) {
        int  i = base + j;
        bool v = act && (i < FLEN - 1);
        float e  = v ? __expf(f[j]) : 0.f;    // |f|<~3: unstable softmax identical
        float fr = fmaf((float)(i - 99), 0.02f, -1.0f);   // ((i+1)-100)/100*2-1
        double de = (double)e;
        tE += de;
        tG  = fma(de, (double)fr, tG);
        cE[j] = tE; cG[j] = tG;
    }

    // ---- wave inclusive scan of lane totals (fp64) ----
    double sE = tE, sG = tG;
    #pragma unroll
    for (int d = 1; d < 64; d <<= 1) {
        double a = __shfl_up(sE, d), b = __shfl_up(sG, d);
        if (lane >= d) { sE += a; sG += b; }
    }
    const double xE = sE - tE, xG = sG - tG;   // exclusive prefix of lane totals

    if (lane == 63) eg[0] = make_double2(0.0, 0.0);
    #pragma unroll
    for (int j = 0; j < 5; ++j) {
        int i = base + j;
        if (act && i <= FLEN - 2)
            eg[i + 1] = make_double2(xE + cE[j], xG + cG[j]);
    }

    // ---- wave-local LDS fence (this wave is sole owner of its row slice;
    //      same-wave DS ops execute in order — no s_barrier needed) ----
    __builtin_amdgcn_wave_barrier();
    __asm__ volatile("s_waitcnt lgkmcnt(0)" ::: "memory");
    __builtin_amdgcn_wave_barrier();

    // ---- per-segment softargmax = prefix difference; O(1) per segment ----
    const int nseg = (P > 0) ? P : 1;
    float sum_in = 0.f; int any_in = 0;
    float nsq_l[3]; int nsq_n = 0;           // this lane's nsq values (<=3 segs/lane)
    for (int s = lane; s < nseg; s += 64) {
        int im = (s > 0) ? s - 1 : 0;
        int ip = (s < P - 1) ? s + 1 : im;
        int pm = ps[im], pc = ps[(P > 0) ? s : 0], pn = ps[ip];
        int lo = (s == 0)        ? 0        : ((pm + pc) >> 1);
        int hi = (s == nseg - 1) ? FLEN - 1 : ((pc + pn) >> 1);
        double2 a = eg[lo], b = eg[hi];
        float den = (float)(b.x - a.x);         // exact to ~1e-13, > 0
        float num = (float)(b.y - a.y);
        float sm  = num / den;
        float nsq = -(sm * sm);
        bool  ii  = (sm > -1.0f) && (sm < 1.0f);
        if (ii) { sum_in += nsq; any_in = 1; }
        if (nsq_n < 3) nsq_l[nsq_n] = nsq;
        nsq_n += 1;
    }

    // ---- common path: some segment in-interval (one ballot decides) ----
    if (__ballot(any_in) != 0ull) {
        #pragma unroll
        for (int d = 32; d >= 1; d >>= 1) sum_in += __shfl_xor(sum_in, d);
        if (lane == 0) out[row] = sum_in;
    } else {
        // rare fallback: sum of two largest nsq among valid segments
        float m1 = -__builtin_inff(), m2 = -__builtin_inff();
        for (int q = 0; q < nsq_n; ++q) {
            float nsq = nsq_l[q];
            if (nsq > m1) { m2 = m1; m1 = nsq; } else { m2 = fmaxf(m2, nsq); }
        }
        #pragma unroll
        for (int d = 32; d >= 1; d >>= 1) {
            float o1 = __shfl_xor(m1, d);
            float o2 = __shfl_xor(m2, d);
            float n1 = fmaxf(m1, o1);
            float n2 = fmaxf(fminf(m1, o1), fmaxf(m2, o2));
            m1 = n1; m2 = n2;
        }
        if (lane == 0) {
            float t2 = m1 + ((m2 > -__builtin_inff()) ? m2 : 0.0f);
            out[row] = t2;
        }
    }
}

extern "C" void kernel_launch(void* const* d_in, const int* in_sizes, int n_in,
                              void* d_out, int out_size, void* d_ws, size_t ws_size,
                              hipStream_t stream) {
    const float* in  = (const float*)d_in[0];
    float*       out = (float*)d_out;
    const int B = in_sizes[0] / FLEN;          // 65536

    // Gaussian kernel sigma=2, l=7: double, normalized, rounded to fp32
    // (matching jnp.asarray(k/k.sum(), float32)), widened back to double.
    double k[7], s = 0.0;
    for (int t = 0; t < 7; ++t) {
        double x = -3.0 + (double)t;
        k[t] = exp(-0.5 * x * x / 4.0);
        s += k[t];
    }
    double bk0 = (double)(float)(k[0] / s);
    double bk1 = (double)(float)(k[1] / s);
    double bk2 = (double)(float)(k[2] / s);
    double bk3 = (double)(float)(k[3] / s);

    pil_kernel<<<B / RPB, 128, 0, stream>>>(in, out, bk0, bk1, bk2, bk3);
}